// Round 11
// baseline (318.004 us; speedup 1.0000x reference)
//
#include <hip/hip_runtime.h>
#include <math.h>

// Problem constants (from setup_inputs):
#define T_STEPS   4
#define NODE_NUM  10000
#define NUM_NODES 50000
#define E         256     // embedding dim
#define TWO_E     512
#define CC        128     // C
#define TWO_C     256
#define ROWS      32      // rows per block (R8 proved 16 worse: B-load amortization)
#define NROWS_ALL (T_STEPS * NODE_NUM)
#define MAX_SLOTS 20000   // dup keys have >=2 rows each -> <= 40000/2 slots

typedef short bf16x8 __attribute__((ext_vector_type(8)));   // 8 bf16 = 4 VGPRs
typedef float f32x4  __attribute__((ext_vector_type(4)));   // MFMA accumulator

#define MFMA16(a, b, c) __builtin_amdgcn_mfma_f32_16x16x32_bf16((a), (b), (c), 0, 0, 0)

// bf16 weights, transposed [N][K], module-scope device global.
// layout (elements): w1t @0 (512x256), w2t @131072 (128x512),
//                    w1ut @196608 (256x128), w2ut @229376 (256x256)
static __device__ unsigned short g_wt[294912];
// per-(t, idx) occurrence count; rows with cnt==1 (~82%) read x directly.
static __device__ int g_cnt[T_STEPS * NUM_NODES];
// per-key compact slot id (valid only when cnt>=2)
static __device__ int g_slot[T_STEPS * NUM_NODES];
static __device__ int g_nslots;
// compacted list of duplicate rows (single list, no slabs)
static __device__ int g_dup[NROWS_ALL];
static __device__ int g_ndup0;

// tanh-form GELU (validated R7: absmax unchanged, VALUBusy 27->17%)
__device__ __forceinline__ float geluf(float v) {
    float p = v * (1.5957691216057308f + 0.07135481282636226f * v * v);
    return v / (1.0f + __expf(-p));
}

// fp32 -> bf16 round-to-nearest-even (finite inputs only)
__device__ __forceinline__ unsigned short f2bf(float f) {
    unsigned int u = __builtin_bit_cast(unsigned int, f);
    u += 0x7fffu + ((u >> 16) & 1u);
    return (unsigned short)(u >> 16);
}

// ---- weight prep: fp32 [K][N] -> bf16 [N][K]; zero cnt/counters/ctable ----
// grid 784 * 256 = 200704 threads covers all sections.
__global__ void prep_weights(float* __restrict__ ctable,
                             const float* __restrict__ W1d, const float* __restrict__ W2d,
                             const float* __restrict__ W1u, const float* __restrict__ W2u) {
    int i = blockIdx.x * 256 + threadIdx.x;       // 0 .. 200703
    if (i == 0) { g_nslots = 0; g_ndup0 = 0; }
    if (i < T_STEPS * NUM_NODES) g_cnt[i] = 0;    // 200000 counts
    // zero the compact dup-sum table: MAX_SLOTS*E floats = 5.12M -> 1.28M float4
    {
        float4 z = make_float4(0.f, 0.f, 0.f, 0.f);
        float4* ct4 = reinterpret_cast<float4*>(ctable);
        for (int j = i; j < MAX_SLOTS * E / 4; j += 200704) ct4[j] = z;
    }
    if (i < 131072) {  // w1t: [512][256] <- W1d [256][512]
        int n = i >> 8, k = i & 255;
        g_wt[i] = f2bf(W1d[(size_t)k * TWO_E + n]);
    }
    if (i < 65536) {   // w2t: [128][512] <- W2d [512][128]
        int n = i >> 9, k = i & 511;
        g_wt[131072 + i] = f2bf(W2d[(size_t)k * CC + n]);
    }
    if (i < 32768) {   // w1ut: [256][128] <- W1u [128][256]
        int n = i >> 7, k = i & 127;
        g_wt[196608 + i] = f2bf(W1u[(size_t)k * TWO_C + n]);
    }
    if (i < 65536) {   // w2ut: [256][256] <- W2u [256][256]
        int n = i >> 8, k = i & 255;
        g_wt[229376 + i] = f2bf(W2u[(size_t)k * E + n]);
    }
}

// ---------------- count occurrences of each (t, idx) ----------------
__global__ void count_kernel(const int* __restrict__ indices) {
    int gr = blockIdx.x * 256 + threadIdx.x;
    if (gr < NROWS_ALL) {
        int t = gr / NODE_NUM;
        atomicAdd(&g_cnt[t * NUM_NODES + indices[gr]], 1);
    }
}

// ---- fused: per-key slot assignment + dup-row list compaction ----
__global__ void index_prep_kernel(const int* __restrict__ indices) {
    int i = blockIdx.x * 256 + threadIdx.x;       // 0 .. 200703
    if (i < T_STEPS * NUM_NODES && g_cnt[i] >= 2)
        g_slot[i] = atomicAdd(&g_nslots, 1);
    if (i < NROWS_ALL) {
        int t = i / NODE_NUM;
        if (g_cnt[t * NUM_NODES + indices[i]] >= 2) {
            int p = atomicAdd(&g_ndup0, 1);
            g_dup[p] = i;
        }
    }
}

// ---- scatter-add dup rows into the compact table, from the compacted list ----
__global__ void scatter_list_kernel(float* __restrict__ ctable,
                                    const float* __restrict__ x,
                                    const int* __restrict__ indices) {
    int nd = g_ndup0;
    for (int e = blockIdx.x; e < nd; e += gridDim.x) {
        int gr = g_dup[e];
        int t = gr / NODE_NUM;
        int slot = g_slot[t * NUM_NODES + indices[gr]];
        atomicAdd(&ctable[(size_t)slot * E + threadIdx.x],
                  x[(size_t)gr * E + threadIdx.x]);
    }
}

// ---------------- fused gather -> LN_d -> MLP_d -> LN_u -> MLP_u ----------------
// R11: SINGLE dispatch over all 40000 rows (1250 blocks). Prior rounds ran 4
// slab dispatches of 313 blocks each -> only ~40% machine fill (matches the
// 26-37% OccupancyPercent plateau across R0-R10: grid-limited, not
// LDS/VGPR-limited). Body = R9's (best measured: 144us, 84 VGPR): ROWS=32,
// 50.7KB two-region LDS, B-fragment double-buffer in every GEMM.
//   region A [0, 33280):     Xf fp32 [32][260]  ->  H1 bf16 [32][520]
//                            -> H2b bf16 [32][136] @0 + G1 bf16 [32][264] @8704
//   region B [33280, 50176): Xs bf16 [32][264]  ->  H2f fp32 [32][132]
__global__ __launch_bounds__(256, 3)
void mlp_kernel(const float* __restrict__ ctable,
                const float* __restrict__ x,
                const float* __restrict__ batched_x,
                const int* __restrict__ indices,
                const float* __restrict__ lnd_s, const float* __restrict__ lnd_b,
                const float* __restrict__ b1d, const float* __restrict__ b2d,
                const float* __restrict__ lnu_s, const float* __restrict__ lnu_b,
                const float* __restrict__ b1u, const float* __restrict__ b2u,
                float* __restrict__ out,
                int grLim) {
    __shared__ __align__(16) unsigned char smem[50176];
    __shared__ const float* rptr[ROWS];
    __shared__ int    ridx[ROWS];

    float*          Xf  = (float*)smem;                         // [32][260]
    unsigned short* Xs  = (unsigned short*)(smem + 33280);      // [32][264]
    unsigned short* H1  = (unsigned short*)smem;                // [32][520]
    float*          H2f = (float*)(smem + 33280);               // [32][132]
    unsigned short* H2b = (unsigned short*)smem;                // [32][136]
    unsigned short* G1  = (unsigned short*)(smem + 8704);       // [32][264]

    const unsigned short* w1t  = g_wt;
    const unsigned short* w2t  = g_wt + 131072;
    const unsigned short* w1ut = g_wt + 196608;
    const unsigned short* w2ut = g_wt + 229376;

    const int tid = threadIdx.x;
    const int w = tid >> 6, lane = tid & 63;
    const int l16 = lane & 15, quad = lane >> 4;
    const int grb = blockIdx.x * ROWS;

    if (tid < ROWS) {
        int gr = grb + tid;
        if (gr >= grLim) gr = grLim - 1;     // never taken (40000%32==0); safety
        int t = gr / NODE_NUM;
        int key = t * NUM_NODES + indices[gr];
        ridx[tid] = indices[gr];
        // unique index (~82%): row input is just x[gr]; dup: compact summed row
        rptr[tid] = (g_cnt[key] > 1)
            ? (ctable + (size_t)g_slot[key] * E)
            : (x + (size_t)gr * E);
    }
    __syncthreads();

    // ---- gather: Xf = row_src + batched_x_row (fp32) ----
    #pragma unroll
    for (int it = 0; it < 8; ++it) {
        int v = it * 256 + tid;
        int r = v >> 6;
        int c = (v & 63) * 4;
        float4 tv = *reinterpret_cast<const float4*>(rptr[r] + c);
        float4 bv = *reinterpret_cast<const float4*>(&batched_x[(size_t)ridx[r] * E + c]);
        float4 s; s.x = tv.x + bv.x; s.y = tv.y + bv.y; s.z = tv.z + bv.z; s.w = tv.w + bv.w;
        *reinterpret_cast<float4*>(&Xf[r * 260 + c]) = s;
    }
    __syncthreads();

    // ---- LN_d (E=256): 8 lanes/row, then cvt bf16 -> Xs ----
    {
        int row = tid >> 3, l8 = tid & 7;
        float s = 0.f, sq = 0.f;
        #pragma unroll
        for (int k = 0; k < 32; ++k) {
            float v = Xf[row * 260 + k * 8 + l8];
            s += v; sq += v * v;
        }
        s  += __shfl_xor(s, 1);  s  += __shfl_xor(s, 2);  s  += __shfl_xor(s, 4);
        sq += __shfl_xor(sq, 1); sq += __shfl_xor(sq, 2); sq += __shfl_xor(sq, 4);
        float mu = s * (1.0f / E);
        float var = sq * (1.0f / E) - mu * mu;
        float rs = rsqrtf(var + 1e-5f);
        #pragma unroll
        for (int k = 0; k < 32; ++k) {
            int c = k * 8 + l8;
            float v = (Xf[row * 260 + c] - mu) * rs * lnd_s[c] + lnd_b[c];
            Xs[row * 264 + c] = f2bf(v);
        }
    }
    __syncthreads();

    // ---- GEMM1: H1[32][512] = gelu(Xs @ W1d + b1d), K=256, B double-buffered ----
    {
        bf16x8 af[2][8];
        #pragma unroll
        for (int mt = 0; mt < 2; ++mt) {
            const unsigned short* base = Xs + (l16 + 16 * mt) * 264 + quad * 8;
            #pragma unroll
            for (int ks = 0; ks < 8; ++ks)
                af[mt][ks] = *reinterpret_cast<const bf16x8*>(base + ks * 32);
        }
        bf16x8 bbuf[2][8];
        {   // prefetch nt=0
            const unsigned short* bp = w1t + (size_t)((w * 8) * 16 + l16) * 256 + quad * 8;
            #pragma unroll
            for (int ks = 0; ks < 8; ++ks)
                bbuf[0][ks] = *reinterpret_cast<const bf16x8*>(bp + ks * 32);
        }
        #pragma unroll
        for (int nt_ = 0; nt_ < 8; ++nt_) {
            const int cb = nt_ & 1, nb = cb ^ 1;       // compile-time after unroll
            if (nt_ < 7) {
                const unsigned short* bp =
                    w1t + (size_t)((w * 8 + nt_ + 1) * 16 + l16) * 256 + quad * 8;
                #pragma unroll
                for (int ks = 0; ks < 8; ++ks)
                    bbuf[nb][ks] = *reinterpret_cast<const bf16x8*>(bp + ks * 32);
            }
            int n = (w * 8 + nt_) * 16 + l16;
            f32x4 a0 = {0.f, 0.f, 0.f, 0.f}, a1 = {0.f, 0.f, 0.f, 0.f};
            #pragma unroll
            for (int ks = 0; ks < 8; ++ks) {
                a0 = MFMA16(af[0][ks], bbuf[cb][ks], a0);
                a1 = MFMA16(af[1][ks], bbuf[cb][ks], a1);
            }
            float bias = b1d[n];
            #pragma unroll
            for (int reg = 0; reg < 4; ++reg) {
                int r = quad * 4 + reg;
                H1[r * 520 + n]        = f2bf(geluf(a0[reg] + bias));
                H1[(r + 16) * 520 + n] = f2bf(geluf(a1[reg] + bias));
            }
        }
    }
    __syncthreads();

    // ---- GEMM2: H2f[32][128] = H1 @ W2d + b2d (fp32 out), K=512, B dbuf ----
    {
        f32x4 acc2[2][2];
        #pragma unroll
        for (int i = 0; i < 2; ++i)
            #pragma unroll
            for (int j = 0; j < 2; ++j) acc2[i][j] = (f32x4){0.f, 0.f, 0.f, 0.f};
        bf16x8 afk[2][8];
        #pragma unroll
        for (int mt = 0; mt < 2; ++mt) {    // A-frags for kh=0
            const unsigned short* base = H1 + (l16 + 16 * mt) * 520 + quad * 8;
            #pragma unroll
            for (int ks = 0; ks < 8; ++ks)
                afk[mt][ks] = *reinterpret_cast<const bf16x8*>(base + ks * 32);
        }
        bf16x8 bbuf[2][8];
        {   // prefetch stage 0 (kh=0, nt2=0)
            const unsigned short* bp = w2t + (size_t)((w * 2) * 16 + l16) * 512 + quad * 8;
            #pragma unroll
            for (int ks = 0; ks < 8; ++ks)
                bbuf[0][ks] = *reinterpret_cast<const bf16x8*>(bp + ks * 32);
        }
        #pragma unroll
        for (int s = 0; s < 4; ++s) {
            const int nt2 = s & 1;
            const int cb = s & 1, nb = cb ^ 1;
            if (s < 3) {
                const int s1 = s + 1, kh1 = s1 >> 1, nt21 = s1 & 1;
                const unsigned short* bp =
                    w2t + (size_t)((w * 2 + nt21) * 16 + l16) * 512 + kh1 * 256 + quad * 8;
                #pragma unroll
                for (int ks = 0; ks < 8; ++ks)
                    bbuf[nb][ks] = *reinterpret_cast<const bf16x8*>(bp + ks * 32);
            }
            if (s == 2) {   // A-frags for kh=1 (LDS, fast)
                #pragma unroll
                for (int mt = 0; mt < 2; ++mt) {
                    const unsigned short* base = H1 + (l16 + 16 * mt) * 520 + 256 + quad * 8;
                    #pragma unroll
                    for (int ks = 0; ks < 8; ++ks)
                        afk[mt][ks] = *reinterpret_cast<const bf16x8*>(base + ks * 32);
                }
            }
            #pragma unroll
            for (int ks = 0; ks < 8; ++ks) {
                acc2[nt2][0] = MFMA16(afk[0][ks], bbuf[cb][ks], acc2[nt2][0]);
                acc2[nt2][1] = MFMA16(afk[1][ks], bbuf[cb][ks], acc2[nt2][1]);
            }
        }
        #pragma unroll
        for (int nt2 = 0; nt2 < 2; ++nt2) {
            int n = (w * 2 + nt2) * 16 + l16;
            float bias = b2d[n];
            #pragma unroll
            for (int mt = 0; mt < 2; ++mt)
                #pragma unroll
                for (int reg = 0; reg < 4; ++reg) {
                    int r = mt * 16 + quad * 4 + reg;
                    H2f[r * 132 + n] = acc2[nt2][mt][reg] + bias;
                }
        }
    }
    __syncthreads();

    // ---- LN_u (C=128): 8 lanes/row, cvt bf16 -> H2b ----
    {
        int row = tid >> 3, l8 = tid & 7;
        float s = 0.f, sq = 0.f;
        #pragma unroll
        for (int k = 0; k < 16; ++k) {
            float v = H2f[row * 132 + k * 8 + l8];
            s += v; sq += v * v;
        }
        s  += __shfl_xor(s, 1);  s  += __shfl_xor(s, 2);  s  += __shfl_xor(s, 4);
        sq += __shfl_xor(sq, 1); sq += __shfl_xor(sq, 2); sq += __shfl_xor(sq, 4);
        float mu = s * (1.0f / CC);
        float var = sq * (1.0f / CC) - mu * mu;
        float rs = rsqrtf(var + 1e-5f);
        #pragma unroll
        for (int k = 0; k < 16; ++k) {
            int c = k * 8 + l8;
            float v = (H2f[row * 132 + c] - mu) * rs * lnu_s[c] + lnu_b[c];
            H2b[row * 136 + c] = f2bf(v);
        }
    }
    __syncthreads();

    // ---- GEMM3: G1[32][256] = gelu(H2b @ W1u + b1u), K=128, B dbuf ----
    {
        bf16x8 af3[2][4];
        #pragma unroll
        for (int mt = 0; mt < 2; ++mt) {
            const unsigned short* base = H2b + (l16 + 16 * mt) * 136 + quad * 8;
            #pragma unroll
            for (int ks = 0; ks < 4; ++ks)
                af3[mt][ks] = *reinterpret_cast<const bf16x8*>(base + ks * 32);
        }
        bf16x8 bbuf[2][4];
        {   // prefetch nt=0
            const unsigned short* bp = w1ut + (size_t)((w * 4) * 16 + l16) * 128 + quad * 8;
            #pragma unroll
            for (int ks = 0; ks < 4; ++ks)
                bbuf[0][ks] = *reinterpret_cast<const bf16x8*>(bp + ks * 32);
        }
        #pragma unroll
        for (int nt_ = 0; nt_ < 4; ++nt_) {
            const int cb = nt_ & 1, nb = cb ^ 1;
            if (nt_ < 3) {
                const unsigned short* bp =
                    w1ut + (size_t)((w * 4 + nt_ + 1) * 16 + l16) * 128 + quad * 8;
                #pragma unroll
                for (int ks = 0; ks < 4; ++ks)
                    bbuf[nb][ks] = *reinterpret_cast<const bf16x8*>(bp + ks * 32);
            }
            int n = (w * 4 + nt_) * 16 + l16;
            f32x4 a0 = {0.f, 0.f, 0.f, 0.f}, a1 = {0.f, 0.f, 0.f, 0.f};
            #pragma unroll
            for (int ks = 0; ks < 4; ++ks) {
                a0 = MFMA16(af3[0][ks], bbuf[cb][ks], a0);
                a1 = MFMA16(af3[1][ks], bbuf[cb][ks], a1);
            }
            float bias = b1u[n];
            #pragma unroll
            for (int reg = 0; reg < 4; ++reg) {
                int r = quad * 4 + reg;
                G1[r * 264 + n]        = f2bf(geluf(a0[reg] + bias));
                G1[(r + 16) * 264 + n] = f2bf(geluf(a1[reg] + bias));
            }
        }
    }
    __syncthreads();

    // ---- GEMM4: out[32][256] = G1 @ W2u + b2u (fp32 global), K=256, B dbuf ----
    {
        bf16x8 af4[2][8];
        #pragma unroll
        for (int mt = 0; mt < 2; ++mt) {
            const unsigned short* base = G1 + (l16 + 16 * mt) * 264 + quad * 8;
            #pragma unroll
            for (int ks = 0; ks < 8; ++ks)
                af4[mt][ks] = *reinterpret_cast<const bf16x8*>(base + ks * 32);
        }
        bf16x8 bbuf[2][8];
        {   // prefetch nt=0
            const unsigned short* bp = w2ut + (size_t)((w * 4) * 16 + l16) * 256 + quad * 8;
            #pragma unroll
            for (int ks = 0; ks < 8; ++ks)
                bbuf[0][ks] = *reinterpret_cast<const bf16x8*>(bp + ks * 32);
        }
        #pragma unroll
        for (int nt_ = 0; nt_ < 4; ++nt_) {
            const int cb = nt_ & 1, nb = cb ^ 1;
            if (nt_ < 3) {
                const unsigned short* bp =
                    w2ut + (size_t)((w * 4 + nt_ + 1) * 16 + l16) * 256 + quad * 8;
                #pragma unroll
                for (int ks = 0; ks < 8; ++ks)
                    bbuf[nb][ks] = *reinterpret_cast<const bf16x8*>(bp + ks * 32);
            }
            int n = (w * 4 + nt_) * 16 + l16;
            f32x4 a0 = {0.f, 0.f, 0.f, 0.f}, a1 = {0.f, 0.f, 0.f, 0.f};
            #pragma unroll
            for (int ks = 0; ks < 8; ++ks) {
                a0 = MFMA16(af4[0][ks], bbuf[cb][ks], a0);
                a1 = MFMA16(af4[1][ks], bbuf[cb][ks], a1);
            }
            float bias = b2u[n];
            #pragma unroll
            for (int reg = 0; reg < 4; ++reg) {
                int r = quad * 4 + reg;
                int g0 = grb + r, g1 = grb + r + 16;
                if (g0 < grLim) out[(size_t)g0 * E + n] = a0[reg] + bias;
                if (g1 < grLim) out[(size_t)g1 * E + n] = a1[reg] + bias;
            }
        }
    }
}

extern "C" void kernel_launch(void* const* d_in, const int* in_sizes, int n_in,
                              void* d_out, int out_size, void* d_ws, size_t ws_size,
                              hipStream_t stream) {
    const float* x     = (const float*)d_in[0];
    const float* bx    = (const float*)d_in[1];
    const int*   idxp  = (const int*)  d_in[2];
    const float* lnd_s = (const float*)d_in[3];
    const float* lnd_b = (const float*)d_in[4];
    const float* W1d   = (const float*)d_in[5];
    const float* b1d   = (const float*)d_in[6];
    const float* W2d   = (const float*)d_in[7];
    const float* b2d   = (const float*)d_in[8];
    const float* lnu_s = (const float*)d_in[9];
    const float* lnu_b = (const float*)d_in[10];
    const float* W1u   = (const float*)d_in[11];
    const float* b1u   = (const float*)d_in[12];
    const float* W2u   = (const float*)d_in[13];
    const float* b2u   = (const float*)d_in[14];
    float* out = (float*)d_out;
    // compact dup-sum table in ws: MAX_SLOTS x E floats = 20.48 MB
    // (ws >= 51.2 MB held in all prior passing rounds: tb>=1 of the old layout)
    float* ctable = (float*)d_ws;
    (void)ws_size; (void)in_sizes; (void)n_in; (void)out_size;

    // 5 dispatches total; ONE mlp dispatch over all 40000 rows (1250 blocks)
    prep_weights<<<784, 256, 0, stream>>>(ctable, W1d, W2d, W1u, W2u);
    count_kernel<<<(NROWS_ALL + 255) / 256, 256, 0, stream>>>(idxp);
    index_prep_kernel<<<784, 256, 0, stream>>>(idxp);
    scatter_list_kernel<<<1024, E, 0, stream>>>(ctable, x, idxp);
    mlp_kernel<<<NROWS_ALL / ROWS, 256, 0, stream>>>(
        ctable, x, bx, idxp, lnd_s, lnd_b, b1d, b2d,
        lnu_s, lnu_b, b1u, b2u, out, NROWS_ALL);
}